// Round 11
// baseline (61.429 us; speedup 1.0000x reference)
//
#include <hip/hip_runtime.h>
#include <math.h>

#define H 1024
#define V 50257
#define L 512

// ws float indices
#define WS_ATTN  0      // 1024 unnormalized attn accum (atomicAdd; memset-zeroed)
#define WS_DEN   1024   // 128 denom partials (plain stores, unique writer)
#define WS_E     1152   // 512 unnormalized exp(logit)
#define WS_X     1664   // 1024 combine output
#define WS_H     2688   // 1024 new h
#define WS_VLOG  3712   // 50257 vocab logits
#define WS_PART  53969  // 2048 per-block vocab exp-sums
#define MEMSET_BYTES 4096   // zeroes WS_ATTN [0,1024)

__device__ __forceinline__ float wave_sum(float v) {
    for (int o = 32; o > 0; o >>= 1) v += __shfl_down(v, o, 64);
    return v;
}
__device__ __forceinline__ float sigf(float x) { return 1.0f / (1.0f + expf(-x)); }
__device__ __forceinline__ float dot4(float4 a, float4 b) {
    return a.x * b.x + a.y * b.y + a.z * b.z + a.w * b.w;
}

// kAB: fused attn logits + (no-max) softmax numerators + unnormalized
// attn_applied. grid 256 x 512; block = (jb = col half, c = 4-row chunk).
// Full-chip (1 block/CU), attn_W redundancy 2x (8 MB). Waves 0-3 compute
// the chunk's 4 logits; jb==0 blocks store e + denom partial (unique
// writers); all 8 waves accumulate 4 enc rows x 512-col half via atomicAdd
// (128 contributors/address - distributed-atomic proven regime).
__global__ __launch_bounds__(512) void kAB(const int* __restrict__ tok,
                                           const float* __restrict__ hidden,
                                           const float* __restrict__ enc,
                                           const float* __restrict__ emb,
                                           const float* __restrict__ attn_W,
                                           const float* __restrict__ attn_b,
                                           float* __restrict__ ws) {
    const int bid = blockIdx.x, t = threadIdx.x;
    const int w = t >> 6, l = t & 63;
    const int jb = bid >> 7, c = bid & 127;
    const size_t token = (size_t)tok[0];
    const float4* ev4 = (const float4*)(emb + token * H);
    const float4* hv4 = (const float4*)hidden;

    __shared__ float esh[4];

    if (w < 4) {
        int r = c * 4 + w;
        const float4* rw = (const float4*)(attn_W + (size_t)r * 2 * H);
        float a = 0.f;
#pragma unroll
        for (int i = 0; i < 4; ++i) {
            a += dot4(rw[i * 64 + l], ev4[i * 64 + l]);
            a += dot4(rw[256 + i * 64 + l], hv4[i * 64 + l]);
        }
        float s = wave_sum(a);
        if (l == 0) esh[w] = expf(s + attn_b[r]);
    }
    __syncthreads();
    if (jb == 0) {
        if (t < 4) ws[WS_E + c * 4 + t] = esh[t];
        if (t == 0) ws[WS_DEN + c] = esh[0] + esh[1] + esh[2] + esh[3];
    }
    int j = jb * 512 + t;
    float acc = 0.f;
#pragma unroll
    for (int i = 0; i < 4; ++i)
        acc += esh[i] * enc[(size_t)(c * 4 + i) * H + j];
    atomicAdd(&ws[WS_ATTN + j], acc);
}

// kC: S = sum of 128 denom partials; x = relu(cwL@emb + (cwR@attn_unnorm)/S
// + b). Blocks 0,1 write attn_weights = e/S. grid 256 x 256, wave per row.
__global__ __launch_bounds__(256) void kC_combine(const int* __restrict__ tok,
                                                  const float* __restrict__ emb,
                                                  const float* __restrict__ comb_W,
                                                  const float* __restrict__ comb_b,
                                                  float* __restrict__ ws,
                                                  float* __restrict__ out) {
    const int bid = blockIdx.x, t = threadIdx.x;
    const int w = t >> 6, l = t & 63;
    __shared__ float red2[2];
    float dv = (t < 128) ? ws[WS_DEN + t] : 0.f;
    if (w < 2) {
        float s = wave_sum(dv);
        if (l == 0) red2[w] = s;
    }
    __syncthreads();
    float invS = 1.0f / (red2[0] + red2[1]);

    if (bid < 2) out[V + 2 * H + bid * 256 + t] = ws[WS_E + bid * 256 + t] * invS;

    const size_t token = (size_t)tok[0];
    const float4* ev4 = (const float4*)(emb + token * H);
    const float4* a4 = (const float4*)(ws + WS_ATTN);
    int r = bid * 4 + w;
    const float4* cw = (const float4*)comb_W;
    float aL = 0.f, aR = 0.f;
#pragma unroll
    for (int i = 0; i < 4; ++i) {
        aL += dot4(cw[(size_t)r * 512 + i * 64 + l], ev4[i * 64 + l]);
        aR += dot4(cw[(size_t)r * 512 + 256 + i * 64 + l], a4[i * 64 + l]);
    }
    float s = wave_sum(aL + aR * invS);
    if (l == 0) ws[WS_X + r] = fmaxf(s + comb_b[r], 0.0f);
}

// kD: gates + LSTM pointwise. grid 1024 x 256: block = unit n, wave = gate.
__global__ __launch_bounds__(256) void kD_gates_lstm(const float* __restrict__ hidden,
                                                     const float* __restrict__ W_ih,
                                                     const float* __restrict__ W_hh,
                                                     const float* __restrict__ b_ih,
                                                     const float* __restrict__ b_hh,
                                                     float* __restrict__ ws,
                                                     float* __restrict__ out) {
    const int n = blockIdx.x, t = threadIdx.x;
    const int w = t >> 6, l = t & 63;
    __shared__ float4 xs[256], hs[256];
    __shared__ float gsh[4];
    xs[t] = ((const float4*)(ws + WS_X))[t];
    hs[t] = ((const float4*)hidden)[t];
    __syncthreads();
    int row = w * H + n;
    const float4* wi = (const float4*)W_ih;
    const float4* wh = (const float4*)W_hh;
    float acc = 0.f;
#pragma unroll
    for (int i = 0; i < 4; ++i) {
        acc += dot4(wi[(size_t)row * 256 + i * 64 + l], xs[i * 64 + l]);
        acc += dot4(wh[(size_t)row * 256 + i * 64 + l], hs[i * 64 + l]);
    }
    float s = wave_sum(acc);
    if (l == 0) gsh[w] = s + b_ih[row] + b_hh[row];
    __syncthreads();
    if (t == 0) {
        float c0 = hidden[n];
        float cc = sigf(gsh[1]) * c0 + sigf(gsh[0]) * tanhf(gsh[2]);
        float hh = sigf(gsh[3]) * tanhf(cc);
        ws[WS_H + n] = hh;
        out[V + n] = hh;
        out[V + H + n] = cc;
    }
}

// kE: vocab logits + per-block exp-sum partial (plain store).
// grid 2048 x 256 = 8 blocks/CU. V = 2048*24 + 1105: blocks < 1105 take
// 25 rows. Stride-4 interleaved wave assignment balances waves (7/6/6/6
// instead of 7/7/7/4 on 25-row blocks), pair-ILP via (k, k+4).
__global__ __launch_bounds__(256) void kE_vocab(const float* __restrict__ out_W,
                                                const float* __restrict__ out_b,
                                                float* __restrict__ ws) {
    const int bid = blockIdx.x, t = threadIdx.x;
    const int w = t >> 6, l = t & 63;
    const int row0 = bid * 24 + (bid < 1105 ? bid : 1105);
    const int cnt  = 24 + (bid < 1105 ? 1 : 0);

    const float4* h4 = (const float4*)(ws + WS_H);
    float4 hr[4];
#pragma unroll
    for (int i = 0; i < 4; ++i) hr[i] = h4[i * 64 + l];

    const float4* ow = (const float4*)out_W;
    float es = 0.f;
    for (int k = w; k < cnt; k += 8) {
        int k1 = k + 4;
        bool has1 = (k1 < cnt);
        int r0 = row0 + k, r1 = row0 + (has1 ? k1 : k);
        const float4* q0 = ow + (size_t)r0 * 256;
        const float4* q1 = ow + (size_t)r1 * 256;
        float a0 = 0.f, a1 = 0.f;
#pragma unroll
        for (int i = 0; i < 4; ++i) {
            a0 += dot4(q0[i * 64 + l], hr[i]);
            a1 += dot4(q1[i * 64 + l], hr[i]);
        }
        float s0 = wave_sum(a0);
        float s1 = wave_sum(a1);
        if (l == 0) {
            float lg0 = s0 + out_b[r0];
            ws[WS_VLOG + r0] = lg0;
            es += expf(lg0);
            if (has1) {
                float lg1 = s1 + out_b[r1];
                ws[WS_VLOG + r1] = lg1;
                es += expf(lg1);
            }
        }
    }
    __shared__ float red[4];
    if (l == 0) red[w] = es;
    __syncthreads();
    if (t == 0) ws[WS_PART + bid] = red[0] + red[1] + red[2] + red[3];
}

// kF: redundant deterministic sum of 2048 partials (= 8*256 exact) + write
// own slice. grid 256 x 256. V = 256*196 + 81.
__global__ __launch_bounds__(256) void kF_logsoftmax(const float* __restrict__ ws,
                                                     float* __restrict__ out) {
    const int bid = blockIdx.x, t = threadIdx.x;
    float ps = 0.f;
#pragma unroll
    for (int k = 0; k < 8; ++k) ps += ws[WS_PART + k * 256 + t];
    float s = wave_sum(ps);
    __shared__ float red[4];
    __shared__ float lsh;
    if ((t & 63) == 0) red[t >> 6] = s;
    __syncthreads();
    if (t == 0) lsh = logf(red[0] + red[1] + red[2] + red[3]);
    __syncthreads();
    float lse = lsh;
    const int row0 = bid * 196 + (bid < 81 ? bid : 81);
    const int cnt  = 196 + (bid < 81 ? 1 : 0);
    for (int i = t; i < cnt; i += 256)
        out[row0 + i] = ws[WS_VLOG + row0 + i] - lse;
}

extern "C" void kernel_launch(void* const* d_in, const int* in_sizes, int n_in,
                              void* d_out, int out_size, void* d_ws, size_t ws_size,
                              hipStream_t stream) {
    const int*   tok     = (const int*)d_in[0];
    const float* hidden  = (const float*)d_in[1];
    const float* enc     = (const float*)d_in[2];
    const float* emb     = (const float*)d_in[3];
    const float* attn_W  = (const float*)d_in[4];
    const float* attn_b  = (const float*)d_in[5];
    const float* comb_W  = (const float*)d_in[6];
    const float* comb_b  = (const float*)d_in[7];
    const float* W_ih    = (const float*)d_in[8];
    const float* W_hh    = (const float*)d_in[9];
    const float* b_ih    = (const float*)d_in[10];
    const float* b_hh    = (const float*)d_in[11];
    const float* out_W   = (const float*)d_in[12];
    const float* out_b   = (const float*)d_in[13];
    float* out = (float*)d_out;
    float* ws  = (float*)d_ws;

    (void)hipMemsetAsync(ws, 0, MEMSET_BYTES, stream);   // zero attn accumulator
    kAB<<<256, 512, 0, stream>>>(tok, hidden, enc, emb, attn_W, attn_b, ws);
    kC_combine<<<256, 256, 0, stream>>>(tok, emb, comb_W, comb_b, ws, out);
    kD_gates_lstm<<<1024, 256, 0, stream>>>(hidden, W_ih, W_hh, b_ih, b_hh, ws, out);
    kE_vocab<<<2048, 256, 0, stream>>>(out_W, out_b, ws);
    kF_logsoftmax<<<256, 256, 0, stream>>>(ws, out);
}

// Round 12
// 59.951 us; speedup vs baseline: 1.0247x; 1.0247x over previous
//
#include <hip/hip_runtime.h>
#include <math.h>

#define H 1024
#define V 50257
#define L 512

// ws float indices
#define WS_ATTN  0      // 1024 unnormalized attn accum (atomicAdd; memset-zeroed)
#define WS_DEN   1024   // 64 denom partials (plain stores, unique writer)
#define WS_E     1088   // 512 unnormalized exp(logit)
#define WS_X     1600   // 1024 combine output
#define WS_H     2624   // 1024 new h
#define WS_VLOG  3648   // 50257 vocab logits
#define WS_PART  53905  // 2048 per-block vocab exp-sums
#define MEMSET_BYTES 4096   // zeroes WS_ATTN [0,1024)

__device__ __forceinline__ float wave_sum(float v) {
    for (int o = 32; o > 0; o >>= 1) v += __shfl_down(v, o, 64);
    return v;
}
__device__ __forceinline__ float sigf(float x) { return 1.0f / (1.0f + expf(-x)); }
__device__ __forceinline__ float dot4(float4 a, float4 b) {
    return a.x * b.x + a.y * b.y + a.z * b.z + a.w * b.w;
}

// kAB: fused attn logits + (no-max) softmax numerators + unnormalized
// attn_applied. grid 256 x 256; block = (jb = col quarter, c = 8-logit chunk).
// Full-chip: 1 block/CU. attn_W redundancy 4x (16 MB, L3/HBM ~2.5 us).
// jb==0 blocks store e and the chunk denom partial (unique writers).
// atomicAdd: 65536 adds over 64 lines (distributed-atomic proven regime).
__global__ __launch_bounds__(256) void kAB(const int* __restrict__ tok,
                                           const float* __restrict__ hidden,
                                           const float* __restrict__ enc,
                                           const float* __restrict__ emb,
                                           const float* __restrict__ attn_W,
                                           const float* __restrict__ attn_b,
                                           float* __restrict__ ws) {
    const int bid = blockIdx.x, t = threadIdx.x;
    const int w = t >> 6, l = t & 63;
    const int jb = bid >> 6, c = bid & 63;
    const size_t token = (size_t)tok[0];
    const float4* ev4 = (const float4*)(emb + token * H);
    const float4* hv4 = (const float4*)hidden;

    __shared__ float esh[8];

    // wave w computes logits r = c*8 + w*2 + {0,1} (pair ILP)
    {
        int r0 = c * 8 + w * 2;
        int r1 = r0 + 1;
        const float4* rw0 = (const float4*)(attn_W + (size_t)r0 * 2 * H);
        const float4* rw1 = (const float4*)(attn_W + (size_t)r1 * 2 * H);
        float a0 = 0.f, a1 = 0.f;
#pragma unroll
        for (int i = 0; i < 4; ++i) {
            float4 e4 = ev4[i * 64 + l], h4 = hv4[i * 64 + l];
            a0 += dot4(rw0[i * 64 + l], e4) + dot4(rw0[256 + i * 64 + l], h4);
            a1 += dot4(rw1[i * 64 + l], e4) + dot4(rw1[256 + i * 64 + l], h4);
        }
        float s0 = wave_sum(a0);
        float s1 = wave_sum(a1);
        if (l == 0) {
            esh[w * 2]     = expf(s0 + attn_b[r0]);
            esh[w * 2 + 1] = expf(s1 + attn_b[r1]);
        }
    }
    __syncthreads();
    if (jb == 0) {
        if (t < 8) ws[WS_E + c * 8 + t] = esh[t];
        if (t == 0) {
            float p = 0.f;
#pragma unroll
            for (int i = 0; i < 8; ++i) p += esh[i];
            ws[WS_DEN + c] = p;   // unique writer per c
        }
    }
    // unnormalized attn accumulate: 8 enc rows x this block's 256-col quarter
    int j = jb * 256 + t;
    float acc = 0.f;
#pragma unroll
    for (int i = 0; i < 8; ++i)
        acc += esh[i] * enc[(size_t)(c * 8 + i) * H + j];
    atomicAdd(&ws[WS_ATTN + j], acc);
}

// kC: S = sum of 64 denom partials (wave 0); x = relu(cwL@emb +
// (cwR@attn_unnorm)/S + b). Blocks 0,1 write attn_weights = e/S.
// grid 256 x 256, wave per row.
__global__ __launch_bounds__(256) void kC_combine(const int* __restrict__ tok,
                                                  const float* __restrict__ emb,
                                                  const float* __restrict__ comb_W,
                                                  const float* __restrict__ comb_b,
                                                  float* __restrict__ ws,
                                                  float* __restrict__ out) {
    const int bid = blockIdx.x, t = threadIdx.x;
    const int w = t >> 6, l = t & 63;
    __shared__ float Ssh;
    float dv = (t < 64) ? ws[WS_DEN + t] : 0.f;
    if (w == 0) {
        float s = wave_sum(dv);
        if (t == 0) Ssh = s;
    }
    __syncthreads();
    float invS = 1.0f / Ssh;

    if (bid < 2) out[V + 2 * H + bid * 256 + t] = ws[WS_E + bid * 256 + t] * invS;

    const size_t token = (size_t)tok[0];
    const float4* ev4 = (const float4*)(emb + token * H);
    const float4* a4 = (const float4*)(ws + WS_ATTN);
    int r = bid * 4 + w;
    const float4* cw = (const float4*)comb_W;
    float aL = 0.f, aR = 0.f;
#pragma unroll
    for (int i = 0; i < 4; ++i) {
        aL += dot4(cw[(size_t)r * 512 + i * 64 + l], ev4[i * 64 + l]);
        aR += dot4(cw[(size_t)r * 512 + 256 + i * 64 + l], a4[i * 64 + l]);
    }
    float s = wave_sum(aL + aR * invS);
    if (l == 0) ws[WS_X + r] = fmaxf(s + comb_b[r], 0.0f);
}

// kD: gates + LSTM pointwise. grid 1024 x 256: block = unit n, wave = gate.
__global__ __launch_bounds__(256) void kD_gates_lstm(const float* __restrict__ hidden,
                                                     const float* __restrict__ W_ih,
                                                     const float* __restrict__ W_hh,
                                                     const float* __restrict__ b_ih,
                                                     const float* __restrict__ b_hh,
                                                     float* __restrict__ ws,
                                                     float* __restrict__ out) {
    const int n = blockIdx.x, t = threadIdx.x;
    const int w = t >> 6, l = t & 63;
    __shared__ float4 xs[256], hs[256];
    __shared__ float gsh[4];
    xs[t] = ((const float4*)(ws + WS_X))[t];
    hs[t] = ((const float4*)hidden)[t];
    __syncthreads();
    int row = w * H + n;
    const float4* wi = (const float4*)W_ih;
    const float4* wh = (const float4*)W_hh;
    float acc = 0.f;
#pragma unroll
    for (int i = 0; i < 4; ++i) {
        acc += dot4(wi[(size_t)row * 256 + i * 64 + l], xs[i * 64 + l]);
        acc += dot4(wh[(size_t)row * 256 + i * 64 + l], hs[i * 64 + l]);
    }
    float s = wave_sum(acc);
    if (l == 0) gsh[w] = s + b_ih[row] + b_hh[row];
    __syncthreads();
    if (t == 0) {
        float c0 = hidden[n];
        float cc = sigf(gsh[1]) * c0 + sigf(gsh[0]) * tanhf(gsh[2]);
        float hh = sigf(gsh[3]) * tanhf(cc);
        ws[WS_H + n] = hh;
        out[V + n] = hh;
        out[V + H + n] = cc;
    }
}

// kE: vocab logits + per-block exp-sum partial (plain store).
// grid 2048 x 256 = exactly 8 blocks/CU (32 waves/CU, max occupancy).
// V = 2048*24 + 1105: blocks < 1105 take 25 rows.
__global__ __launch_bounds__(256) void kE_vocab(const float* __restrict__ out_W,
                                                const float* __restrict__ out_b,
                                                float* __restrict__ ws) {
    const int bid = blockIdx.x, t = threadIdx.x;
    const int w = t >> 6, l = t & 63;
    const int row0 = bid * 24 + (bid < 1105 ? bid : 1105);
    const int cnt  = 24 + (bid < 1105 ? 1 : 0);

    const float4* h4 = (const float4*)(ws + WS_H);
    float4 hr[4];
#pragma unroll
    for (int i = 0; i < 4; ++i) hr[i] = h4[i * 64 + l];

    const float4* ow = (const float4*)out_W;
    float es = 0.f;
    int wq = (cnt + 3) >> 2;
    int kb = w * wq;
    int ke = kb + wq < cnt ? kb + wq : cnt;
    for (int k = kb; k < ke; k += 2) {
        bool has1 = (k + 1 < ke);
        int k1 = has1 ? k + 1 : k;
        int r0 = row0 + k, r1 = row0 + k1;
        const float4* q0 = ow + (size_t)r0 * 256;
        const float4* q1 = ow + (size_t)r1 * 256;
        float a0 = 0.f, a1 = 0.f;
#pragma unroll
        for (int i = 0; i < 4; ++i) {
            a0 += dot4(q0[i * 64 + l], hr[i]);
            a1 += dot4(q1[i * 64 + l], hr[i]);
        }
        float s0 = wave_sum(a0);
        float s1 = wave_sum(a1);
        if (l == 0) {
            float lg0 = s0 + out_b[r0];
            ws[WS_VLOG + r0] = lg0;
            es += expf(lg0);
            if (has1) {
                float lg1 = s1 + out_b[r1];
                ws[WS_VLOG + r1] = lg1;
                es += expf(lg1);
            }
        }
    }
    __shared__ float red[4];
    if (l == 0) red[w] = es;
    __syncthreads();
    if (t == 0) ws[WS_PART + bid] = red[0] + red[1] + red[2] + red[3];
}

// kF: redundant deterministic sum of 2048 partials (= 8*256 exact) + write
// own slice. grid 256 x 256. V = 256*196 + 81.
__global__ __launch_bounds__(256) void kF_logsoftmax(const float* __restrict__ ws,
                                                     float* __restrict__ out) {
    const int bid = blockIdx.x, t = threadIdx.x;
    float ps = 0.f;
#pragma unroll
    for (int k = 0; k < 8; ++k) ps += ws[WS_PART + k * 256 + t];
    float s = wave_sum(ps);
    __shared__ float red[4];
    __shared__ float lsh;
    if ((t & 63) == 0) red[t >> 6] = s;
    __syncthreads();
    if (t == 0) lsh = logf(red[0] + red[1] + red[2] + red[3]);
    __syncthreads();
    float lse = lsh;
    const int row0 = bid * 196 + (bid < 81 ? bid : 81);
    const int cnt  = 196 + (bid < 81 ? 1 : 0);
    for (int i = t; i < cnt; i += 256)
        out[row0 + i] = ws[WS_VLOG + row0 + i] - lse;
}

extern "C" void kernel_launch(void* const* d_in, const int* in_sizes, int n_in,
                              void* d_out, int out_size, void* d_ws, size_t ws_size,
                              hipStream_t stream) {
    const int*   tok     = (const int*)d_in[0];
    const float* hidden  = (const float*)d_in[1];
    const float* enc     = (const float*)d_in[2];
    const float* emb     = (const float*)d_in[3];
    const float* attn_W  = (const float*)d_in[4];
    const float* attn_b  = (const float*)d_in[5];
    const float* comb_W  = (const float*)d_in[6];
    const float* comb_b  = (const float*)d_in[7];
    const float* W_ih    = (const float*)d_in[8];
    const float* W_hh    = (const float*)d_in[9];
    const float* b_ih    = (const float*)d_in[10];
    const float* b_hh    = (const float*)d_in[11];
    const float* out_W   = (const float*)d_in[12];
    const float* out_b   = (const float*)d_in[13];
    float* out = (float*)d_out;
    float* ws  = (float*)d_ws;

    (void)hipMemsetAsync(ws, 0, MEMSET_BYTES, stream);   // zero attn accumulator
    kAB<<<256, 256, 0, stream>>>(tok, hidden, enc, emb, attn_W, attn_b, ws);
    kC_combine<<<256, 256, 0, stream>>>(tok, emb, comb_W, comb_b, ws, out);
    kD_gates_lstm<<<1024, 256, 0, stream>>>(hidden, W_ih, W_hh, b_ih, b_hh, ws, out);
    kE_vocab<<<2048, 256, 0, stream>>>(out_W, out_b, ws);
    kF_logsoftmax<<<256, 256, 0, stream>>>(ws, out);
}